// Round 17
// baseline (151.022 us; speedup 1.0000x reference)
//
#include <hip/hip_runtime.h>
#include <math.h>

#define BB 32
#define SS 2048
#define HH 1024
#define AA 256
#define NEGV (-1e20f)
#define BK 32
#define NT (HH / BK)    // 32
#define NG 16           // k34 groups per batch; each owns 128 rows

typedef _Float16 half8 __attribute__((ext_vector_type(8)));
typedef float f32x4 __attribute__((ext_vector_type(4)));

__device__ inline void async_lds16(const void* g, void* l) {
    __builtin_amdgcn_global_load_lds(
        (const __attribute__((address_space(1))) unsigned int*)g,
        (__attribute__((address_space(3))) unsigned int*)l, 16, 0, 0);
}

__device__ inline f32x4 gload4(const float* p) {
    f32x4 r;
    asm volatile("global_load_dwordx4 %0, %1, off"
                 : "=&v"(r) : "v"(p) : "memory");
    return r;
}

__device__ inline half8 cvt8(f32x4 a, f32x4 b) {
    half8 h;
    h[0] = (_Float16)a[0]; h[1] = (_Float16)a[1];
    h[2] = (_Float16)a[2]; h[3] = (_Float16)a[3];
    h[4] = (_Float16)b[0]; h[5] = (_Float16)b[1];
    h[6] = (_Float16)b[2]; h[7] = (_Float16)b[3];
    return h;
}
__device__ inline half8 cvt8f(float4 a, float4 b) {
    half8 h;
    h[0] = (_Float16)a.x; h[1] = (_Float16)a.y;
    h[2] = (_Float16)a.z; h[3] = (_Float16)a.w;
    h[4] = (_Float16)b.x; h[5] = (_Float16)b.y;
    h[6] = (_Float16)b.z; h[7] = (_Float16)b.w;
    return h;
}

// ============ PREP ==========================================================
// [0,128):   W1 -> f16 K-major tiles
// [128,160): ctx GEMV, a-octet blocks, W2+h_t LDS-staged (L2 traffic 33->5 MB)
// [160,192): compact list + yidx (scatter source row, or -1 if unmasked)
// [192,224): zero out (for k34 atomics)
__global__ __launch_bounds__(256) void k_prep(const float* __restrict__ W,
                                              const float* __restrict__ h_t,
                                              const float* __restrict__ bias,
                                              const int* __restrict__ mask,
                                              _Float16* __restrict__ W16t,
                                              float* __restrict__ c,
                                              int* __restrict__ sList,
                                              int* __restrict__ cntb,
                                              int* __restrict__ yidx,
                                              float* __restrict__ out) {
    const int blk = blockIdx.x;
    const int tid = threadIdx.x;
    const int lane = tid & 63;
    const int wave = tid >> 6;
    __shared__ int lcnt;
    __shared__ float w2s[8][HH];    // 32 KB (role B)
    __shared__ float hts[HH];       // 4 KB  (role B)

    if (blk < 128) {                        // ---- role A: W16 tiled cast
        int idx = blk * 256 + tid;          // unit id, < 32768
        int kt = idx >> 10;
        int u  = idx & 1023;
        int col = u >> 2, ks = u & 3;
        const float* src = W + (size_t)col * 2 * HH + kt * BK + ks * 8;
        float4 a0 = *(const float4*)src;
        float4 a1 = *(const float4*)(src + 4);
        *reinterpret_cast<half8*>(W16t + (size_t)idx * 8) = cvt8f(a0, a1);
        return;
    }
    if (blk < 160) {                        // ---- role B: ctx GEMV (a-octet)
        const int a0 = (blk - 128) * 8;
        for (int i = tid; i < 8 * (HH / 4); i += 256) {
            int a_l = i >> 8;               // / (HH/4)
            int kc = (i & 255) * 4;
            *reinterpret_cast<float4*>(&w2s[a_l][kc]) =
                *reinterpret_cast<const float4*>(&W[(size_t)(a0 + a_l) * 2 * HH + HH + kc]);
        }
        for (int b = 0; b < BB; ++b) {
            __syncthreads();                // protect hts from prev readers
            for (int i = tid; i < HH / 4; i += 256)
                *reinterpret_cast<float4*>(&hts[i * 4]) =
                    *reinterpret_cast<const float4*>(&h_t[(size_t)b * HH + i * 4]);
            __syncthreads();
#pragma unroll
            for (int aw = 0; aw < 2; ++aw) {
                int a_l = wave * 2 + aw;
                float acc = 0.f;
                for (int k = lane; k < HH; k += 64)
                    acc += w2s[a_l][k] * hts[k];
                for (int off = 32; off; off >>= 1)
                    acc += __shfl_down(acc, off, 64);
                if (lane == 0) c[b * AA + a0 + a_l] = acc + bias[a0 + a_l];
            }
        }
        return;
    }
    if (blk >= 192) {                       // ---- role D: zero out buffer
        int i = (blk - 192) * 256 + tid;    // < 8192 f32x4
        *reinterpret_cast<f32x4*>(&out[(size_t)i * 4]) = (f32x4){0.f, 0.f, 0.f, 0.f};
        return;
    }
    // ---- role C: compaction (wave-ballot, unordered) + yidx
    const int b = blk - 160;
    if (tid == 0) lcnt = 0;
    __syncthreads();
    int* lst = sList + b * SS;
#pragma unroll
    for (int i = 0; i < 8; ++i) {
        int s = tid + i * 256;
        int pref = 0, tot = 0;
#pragma unroll
        for (int bb = 0; bb < BB; ++bb) {
            int mv = (mask[bb * SS + s] != 0);
            tot += mv;
            if (bb <= b) pref += mv;
        }
        yidx[b * SS + s] = (mask[b * SS + s] != 0) ? (pref - 1) : -1;
        bool need = (tot > b);
        unsigned long long mk = __ballot(need);
        int wbase = 0;
        if (lane == 0) wbase = atomicAdd(&lcnt, __popcll(mk));
        wbase = __shfl(wbase, 0, 64);
        if (need) lst[wbase + __popcll(mk & ((1ull << lane) - 1))] = s;
    }
    __syncthreads();
    const int m = lcnt;
    if (tid == 0) cntb[b] = m;
    if (m > 0) {
        int padded = (m + 63) & ~63;
        int first = lst[0];
        for (int j = m + tid; j < padded; j += 256) lst[j] = first;
    }
}

// ============ K2: MFMA f16 score GEMM, 64x256 tile (R13 pipelined form) =====
__global__ __launch_bounds__(256, 3) void k2_mfma(const float* __restrict__ h_i,
                                                  const _Float16* __restrict__ W16t,
                                                  const float* __restrict__ c,
                                                  const float* __restrict__ u,
                                                  const int* __restrict__ sList,
                                                  const int* __restrict__ cntb,
                                                  float* __restrict__ y) {
    __shared__ _Float16 Alds[3][4][64][8];    // 12 KB (triple)
    __shared__ _Float16 Blds[2][1024][8];     // 32 KB, unit = col*4+ks
    __shared__ float c_s[AA], u_s[AA];
    __shared__ float red[2][64];
    __shared__ int s_idx[64];

    const int t = blockIdx.x;
    int b = -1, ti = 0, base = 0;
    for (int bb = 0; bb < BB; ++bb) {
        int nt = (cntb[bb] + 63) >> 6;
        if (b < 0 && t < base + nt) { b = bb; ti = t - base; }
        base += nt;
    }
    if (b < 0) return;

    const int tid = threadIdx.x;
    const int lane = tid & 63;
    const int wave = tid >> 6;
    const int wr = wave >> 1;               // 0..1 -> 32-row slab
    const int wc = wave & 1;                // 0..1 -> 128-col slab

    if (tid < 64) s_idx[tid] = sList[b * SS + ti * 64 + tid];
    c_s[tid] = c[b * AA + tid];
    u_s[tid] = u[tid];
    __syncthreads();        // full drain: clean vmcnt state for manual counting

    f32x4 acc[2][8];
#pragma unroll
    for (int rf = 0; rf < 2; ++rf)
#pragma unroll
        for (int cf = 0; cf < 8; ++cf) acc[rf][cf] = (f32x4){0.f, 0.f, 0.f, 0.f};

    const int arow = tid >> 2;              // 0..63
    const int aks = tid & 3;                // 0..3
    const float* Abase = h_i + ((size_t)b * SS + s_idx[arow]) * HH + aks * 8;

    const int sb0 = __builtin_amdgcn_readfirstlane(wave * 256);
    _Float16* Bflat = &Blds[0][0][0];       // one buffer = 8192 halfs (16 KB)

    const int kq = lane >> 4;
    const int lr = lane & 15;

    // ---- prologue: A(0)x2, A(1)x2, B(0)x4, A(2)x2 -> 10 outstanding
    f32x4 r0a = gload4(Abase);
    f32x4 r0b = gload4(Abase + 4);
    f32x4 r1a = gload4(Abase + BK);
    f32x4 r1b = gload4(Abase + BK + 4);
#pragma unroll
    for (int i = 0; i < 4; ++i) {
        int sbase = sb0 + i * 64;
        async_lds16(W16t + (size_t)(sbase + lane) * 8, Bflat + (size_t)sbase * 8);
    }
    f32x4 rAa = gload4(Abase + 2 * BK);
    f32x4 rAb = gload4(Abase + 2 * BK + 4);

    asm volatile("s_waitcnt vmcnt(6)" ::: "memory");   // A(0),A(1) ready
    __builtin_amdgcn_sched_barrier(0);
    *reinterpret_cast<half8*>(&Alds[0][aks][arow][0]) = cvt8(r0a, r0b);
    *reinterpret_cast<half8*>(&Alds[1][aks][arow][0]) = cvt8(r1a, r1b);
    asm volatile("s_waitcnt vmcnt(2) lgkmcnt(0)" ::: "memory");  // B(0) done
    __builtin_amdgcn_sched_barrier(0);
    __builtin_amdgcn_s_barrier();

    for (int t2 = 0; t2 < NT; ++t2) {
        const int cur3 = t2 % 3, curB = t2 & 1;
        if (t2 + 1 < NT) {
#pragma unroll
            for (int i = 0; i < 4; ++i) {
                int sbase = sb0 + i * 64;
                async_lds16(W16t + (size_t)(t2 + 1) * 8192 + (size_t)(sbase + lane) * 8,
                            Bflat + (size_t)((t2 + 1) & 1) * 8192 + (size_t)sbase * 8);
            }
        }
        if (t2 + 2 < NT) {
            asm volatile("s_waitcnt vmcnt(4)" ::: "memory");
            __builtin_amdgcn_sched_barrier(0);
            *reinterpret_cast<half8*>(&Alds[(t2 + 2) % 3][aks][arow][0]) = cvt8(rAa, rAb);
        }
        if (t2 + 3 < NT) {
            rAa = gload4(Abase + (t2 + 3) * BK);
            rAb = gload4(Abase + (t2 + 3) * BK + 4);
        }
        half8 af[2], bf[8];
#pragma unroll
        for (int rf = 0; rf < 2; ++rf)
            af[rf] = *reinterpret_cast<half8*>(&Alds[cur3][kq][wr * 32 + rf * 16 + lr][0]);
#pragma unroll
        for (int cf = 0; cf < 8; ++cf) {
            int col = wc * 128 + cf * 16 + lr;
            bf[cf] = *reinterpret_cast<half8*>(
                Bflat + (size_t)curB * 8192 + (size_t)(col * 4 + kq) * 8);
        }
        __builtin_amdgcn_s_setprio(1);
#pragma unroll
        for (int rf = 0; rf < 2; ++rf)
#pragma unroll
            for (int cf = 0; cf < 8; ++cf)
                acc[rf][cf] = __builtin_amdgcn_mfma_f32_16x16x32_f16(
                    af[rf], bf[cf], acc[rf][cf], 0, 0, 0);
        __builtin_amdgcn_s_setprio(0);
        if (t2 < NT - 1) {
            if (t2 + 3 < NT)
                asm volatile("s_waitcnt vmcnt(2) lgkmcnt(0)" ::: "memory");
            else
                asm volatile("s_waitcnt vmcnt(0) lgkmcnt(0)" ::: "memory");
            __builtin_amdgcn_sched_barrier(0);
            __builtin_amdgcn_s_barrier();
        }
    }

    // ---- epilogue
#pragma unroll
    for (int rf = 0; rf < 2; ++rf) {
#pragma unroll
        for (int j = 0; j < 4; ++j) {
            float v = 0.f;
#pragma unroll
            for (int cf = 0; cf < 8; ++cf) {
                int col = wc * 128 + cf * 16 + lr;
                float z = acc[rf][cf][j] + c_s[col];
                v += tanhf(z) * u_s[col];
            }
            v += __shfl_xor(v, 1, 64);
            v += __shfl_xor(v, 2, 64);
            v += __shfl_xor(v, 4, 64);
            v += __shfl_xor(v, 8, 64);
            if (lr == 0) red[wc][wr * 32 + rf * 16 + kq * 4 + j] = v;
        }
    }
    __syncthreads();
    if (tid < 64) y[(size_t)b * SS + s_idx[tid]] = red[0][tid] + red[1][tid];
}

// ============ K34: stats once; 128-row compact list; unroll-4; atomic out ===
// grid = BB*NG; block (b,grp) owns rows grp*128 .. grp*128+127.
__global__ __launch_bounds__(256) void k34(const float* __restrict__ h_i,
                                           const float* __restrict__ y,
                                           const int* __restrict__ yidx,
                                           float* __restrict__ out) {
    const int blk = blockIdx.x;
    const int b = blk >> 4;
    const int grp = blk & (NG - 1);
    const int tid = threadIdx.x;
    const int lane = tid & 63;
    const int wave = tid >> 6;
    __shared__ float rmax[4], rsum[4];
    __shared__ float aval[128];
    __shared__ int slist[128];
    __shared__ int mtot;

    // ---- row stats, once (yidx = source row or -1)
    float beta[8];
    float mx = -INFINITY;
#pragma unroll
    for (int i = 0; i < 8; ++i) {
        int s = tid + i * 256;
        int p = yidx[b * SS + s];
        int pc = p < 0 ? 0 : p;
        float v = (p >= 0) ? y[(size_t)pc * SS + s] : NEGV;
        beta[i] = v;
        mx = fmaxf(mx, v);
    }
    for (int off = 32; off; off >>= 1) mx = fmaxf(mx, __shfl_xor(mx, off, 64));
    if (lane == 0) rmax[wave] = mx;
    __syncthreads();
    mx = fmaxf(fmaxf(rmax[0], rmax[1]), fmaxf(rmax[2], rmax[3]));
    float sum = 0.f;
#pragma unroll
    for (int i = 0; i < 8; ++i) sum += expf(beta[i] - mx);
    for (int off = 32; off; off >>= 1) sum += __shfl_xor(sum, off, 64);
    if (lane == 0) rsum[wave] = sum;
    __syncthreads();
    sum = rsum[0] + rsum[1] + rsum[2] + rsum[3];
    const float inv = 1.f / sum;

    // ---- wave 0 builds the combined compact list for 4 chunks of 32 rows
    if (wave == 0) {
        int base = 0;
#pragma unroll
        for (int cc = 0; cc < 4; ++cc) {
            int s = grp * 128 + cc * 32 + lane;   // lane<32 valid
            float a = 0.f;
            bool nz = false;
            if (lane < 32) {
                int p = yidx[b * SS + s];
                if (p >= 0) {
                    a = expf(y[(size_t)p * SS + s] - mx) * inv;
                    nz = (a != 0.f);
                }
            }
            unsigned long long mk = __ballot(nz);
            if (nz) {
                int off = base + __popcll(mk & ((1ull << lane) - 1));
                slist[off] = s;
                aval[off] = a;
            }
            base += __popcll(mk);
        }
        if (lane == 0) mtot = base;
    }
    __syncthreads();

    // ---- weighted sum over ≤128 rows, unroll-4
    const int m = mtot;
    const float* basep = h_i + (size_t)b * SS * HH;
    f32x4 a0 = {0,0,0,0}, a1 = {0,0,0,0}, a2 = {0,0,0,0}, a3 = {0,0,0,0};
    int i2 = 0;
    for (; i2 + 4 <= m; i2 += 4) {
        float w0 = aval[i2],     w1 = aval[i2 + 1];
        float w2 = aval[i2 + 2], w3 = aval[i2 + 3];
        float4 v0 = *reinterpret_cast<const float4*>(&basep[(size_t)slist[i2]     * HH + tid * 4]);
        float4 v1 = *reinterpret_cast<const float4*>(&basep[(size_t)slist[i2 + 1] * HH + tid * 4]);
        float4 v2 = *reinterpret_cast<const float4*>(&basep[(size_t)slist[i2 + 2] * HH + tid * 4]);
        float4 v3 = *reinterpret_cast<const float4*>(&basep[(size_t)slist[i2 + 3] * HH + tid * 4]);
        a0[0] += w0 * v0.x; a0[1] += w0 * v0.y; a0[2] += w0 * v0.z; a0[3] += w0 * v0.w;
        a1[0] += w1 * v1.x; a1[1] += w1 * v1.y; a1[2] += w1 * v1.z; a1[3] += w1 * v1.w;
        a2[0] += w2 * v2.x; a2[1] += w2 * v2.y; a2[2] += w2 * v2.z; a2[3] += w2 * v2.w;
        a3[0] += w3 * v3.x; a3[1] += w3 * v3.y; a3[2] += w3 * v3.z; a3[3] += w3 * v3.w;
    }
    for (; i2 < m; ++i2) {
        float w0 = aval[i2];
        float4 v0 = *reinterpret_cast<const float4*>(&basep[(size_t)slist[i2] * HH + tid * 4]);
        a0[0] += w0 * v0.x; a0[1] += w0 * v0.y; a0[2] += w0 * v0.z; a0[3] += w0 * v0.w;
    }
    float r0 = (a0[0] + a1[0]) + (a2[0] + a3[0]);
    float r1 = (a0[1] + a1[1]) + (a2[1] + a3[1]);
    float r2 = (a0[2] + a1[2]) + (a2[2] + a3[2]);
    float r3 = (a0[3] + a1[3]) + (a2[3] + a3[3]);
    float* op = out + (size_t)b * HH + tid * 4;
    unsafeAtomicAdd(op + 0, r0);
    unsafeAtomicAdd(op + 1, r1);
    unsafeAtomicAdd(op + 2, r2);
    unsafeAtomicAdd(op + 3, r3);
}

extern "C" void kernel_launch(void* const* d_in, const int* in_sizes, int n_in,
                              void* d_out, int out_size, void* d_ws, size_t ws_size,
                              hipStream_t stream) {
    const float* h_i  = (const float*)d_in[0];
    const float* h_t  = (const float*)d_in[1];
    const int*   mask = (const int*)d_in[2];
    const float* W    = (const float*)d_in[3];
    const float* bias = (const float*)d_in[4];
    const float* u    = (const float*)d_in[5];
    float* out = (float*)d_out;

    float* c        = (float*)d_ws;                        // 8192
    float* y        = c + BB * AA;                         // 65536
    _Float16* W16t  = (_Float16*)(y + BB * SS);            // 262144 f16
    int* sList      = (int*)(W16t + AA * HH);              // 65536
    int* cntb       = sList + BB * SS;                     // 32
    int* yidx       = cntb + BB;                           // 65536

    k_prep<<<224, 256, 0, stream>>>(W, h_t, bias, mask, W16t, c, sList, cntb, yidx, out);
    k2_mfma<<<1024, 256, 0, stream>>>(h_i, W16t, c, u, sList, cntb, y);
    k34<<<BB * NG, 256, 0, stream>>>(h_i, y, yidx, out);
}

// Round 18
// 97.157 us; speedup vs baseline: 1.5544x; 1.5544x over previous
//
#include <hip/hip_runtime.h>
#include <math.h>

#define BB 32
#define SS 2048
#define HH 1024
#define AA 256
#define NEGV (-1e20f)
#define BK 32
#define NT (HH / BK)    // 32
#define NG 16           // k34 groups per batch; each owns 128 rows

typedef _Float16 half8 __attribute__((ext_vector_type(8)));
typedef float f32x4 __attribute__((ext_vector_type(4)));

__device__ inline void async_lds16(const void* g, void* l) {
    __builtin_amdgcn_global_load_lds(
        (const __attribute__((address_space(1))) unsigned int*)g,
        (__attribute__((address_space(3))) unsigned int*)l, 16, 0, 0);
}

__device__ inline f32x4 gload4(const float* p) {
    f32x4 r;
    asm volatile("global_load_dwordx4 %0, %1, off"
                 : "=&v"(r) : "v"(p) : "memory");
    return r;
}

__device__ inline half8 cvt8(f32x4 a, f32x4 b) {
    half8 h;
    h[0] = (_Float16)a[0]; h[1] = (_Float16)a[1];
    h[2] = (_Float16)a[2]; h[3] = (_Float16)a[3];
    h[4] = (_Float16)b[0]; h[5] = (_Float16)b[1];
    h[6] = (_Float16)b[2]; h[7] = (_Float16)b[3];
    return h;
}
__device__ inline half8 cvt8f(float4 a, float4 b) {
    half8 h;
    h[0] = (_Float16)a.x; h[1] = (_Float16)a.y;
    h[2] = (_Float16)a.z; h[3] = (_Float16)a.w;
    h[4] = (_Float16)b.x; h[5] = (_Float16)b.y;
    h[6] = (_Float16)b.z; h[7] = (_Float16)b.w;
    return h;
}

// ============ PREP ==========================================================
// [0,128):    W1 -> f16 K-major tiles    [128,2176): ctx GEMV (parallel)
// [2176,2208): compact + yidx            [2208,2240): zero out (for atomics)
__global__ __launch_bounds__(256) void k_prep(const float* __restrict__ W,
                                              const float* __restrict__ h_t,
                                              const float* __restrict__ bias,
                                              const int* __restrict__ mask,
                                              _Float16* __restrict__ W16t,
                                              float* __restrict__ c,
                                              int* __restrict__ sList,
                                              int* __restrict__ cntb,
                                              int* __restrict__ yidx,
                                              float* __restrict__ out) {
    const int blk = blockIdx.x;
    const int tid = threadIdx.x;
    __shared__ int lcnt;

    if (blk < 128) {                        // ---- role A: W16 tiled cast
        int idx = blk * 256 + tid;          // unit id, < 32768
        int kt = idx >> 10;
        int u  = idx & 1023;
        int col = u >> 2, ks = u & 3;
        const float* src = W + (size_t)col * 2 * HH + kt * BK + ks * 8;
        float4 a0 = *(const float4*)src;
        float4 a1 = *(const float4*)(src + 4);
        *reinterpret_cast<half8*>(W16t + (size_t)idx * 8) = cvt8f(a0, a1);
        return;
    }
    if (blk < 2176) {                       // ---- role B: ctx GEMV (parallel)
        int wave = tid >> 6;
        int lane = tid & 63;
        int pair = (blk - 128) * 4 + wave;  // < B*A = 8192
        int b = pair >> 8;
        int a = pair & (AA - 1);
        const float* ht = h_t + (size_t)b * HH;
        const float* w2 = W + (size_t)a * 2 * HH + HH;
        float acc = 0.f;
        for (int k = lane; k < HH; k += 64)
            acc += ht[k] * w2[k];
        for (int off = 32; off; off >>= 1)
            acc += __shfl_down(acc, off, 64);
        if (lane == 0) c[pair] = acc + bias[a];
        return;
    }
    if (blk >= 2208) {                      // ---- role D: zero out buffer
        int i = (blk - 2208) * 256 + tid;   // < 8192 f32x4
        *reinterpret_cast<f32x4*>(&out[(size_t)i * 4]) = (f32x4){0.f, 0.f, 0.f, 0.f};
        return;
    }
    // ---- role C: compaction (wave-ballot, unordered) + yidx
    const int b = blk - 2176;
    const int lane = tid & 63;
    if (tid == 0) lcnt = 0;
    __syncthreads();
    int* lst = sList + b * SS;
#pragma unroll
    for (int i = 0; i < 8; ++i) {
        int s = tid + i * 256;
        int pref = 0, tot = 0;
#pragma unroll
        for (int bb = 0; bb < BB; ++bb) {
            int mv = (mask[bb * SS + s] != 0);
            tot += mv;
            if (bb <= b) pref += mv;
        }
        yidx[b * SS + s] = (mask[b * SS + s] != 0) ? (pref - 1) : -1;
        bool need = (tot > b);
        unsigned long long mk = __ballot(need);
        int wbase = 0;
        if (lane == 0) wbase = atomicAdd(&lcnt, __popcll(mk));
        wbase = __shfl(wbase, 0, 64);
        if (need) lst[wbase + __popcll(mk & ((1ull << lane) - 1))] = s;
    }
    __syncthreads();
    const int m = lcnt;
    if (tid == 0) cntb[b] = m;
    if (m > 0) {
        int padded = (m + 63) & ~63;
        int first = lst[0];
        for (int j = m + tid; j < padded; j += 256) lst[j] = first;
    }
}

// ============ K2: MFMA f16 score GEMM, 64x256 tile (R13 pipelined form) =====
__global__ __launch_bounds__(256, 3) void k2_mfma(const float* __restrict__ h_i,
                                                  const _Float16* __restrict__ W16t,
                                                  const float* __restrict__ c,
                                                  const float* __restrict__ u,
                                                  const int* __restrict__ sList,
                                                  const int* __restrict__ cntb,
                                                  float* __restrict__ y) {
    __shared__ _Float16 Alds[3][4][64][8];    // 12 KB (triple)
    __shared__ _Float16 Blds[2][1024][8];     // 32 KB, unit = col*4+ks
    __shared__ float c_s[AA], u_s[AA];
    __shared__ float red[2][64];
    __shared__ int s_idx[64];

    const int t = blockIdx.x;
    int b = -1, ti = 0, base = 0;
    for (int bb = 0; bb < BB; ++bb) {
        int nt = (cntb[bb] + 63) >> 6;
        if (b < 0 && t < base + nt) { b = bb; ti = t - base; }
        base += nt;
    }
    if (b < 0) return;

    const int tid = threadIdx.x;
    const int lane = tid & 63;
    const int wave = tid >> 6;
    const int wr = wave >> 1;               // 0..1 -> 32-row slab
    const int wc = wave & 1;                // 0..1 -> 128-col slab

    if (tid < 64) s_idx[tid] = sList[b * SS + ti * 64 + tid];
    c_s[tid] = c[b * AA + tid];
    u_s[tid] = u[tid];
    __syncthreads();        // full drain: clean vmcnt state for manual counting

    f32x4 acc[2][8];
#pragma unroll
    for (int rf = 0; rf < 2; ++rf)
#pragma unroll
        for (int cf = 0; cf < 8; ++cf) acc[rf][cf] = (f32x4){0.f, 0.f, 0.f, 0.f};

    const int arow = tid >> 2;              // 0..63
    const int aks = tid & 3;                // 0..3
    const float* Abase = h_i + ((size_t)b * SS + s_idx[arow]) * HH + aks * 8;

    const int sb0 = __builtin_amdgcn_readfirstlane(wave * 256);
    _Float16* Bflat = &Blds[0][0][0];       // one buffer = 8192 halfs (16 KB)

    const int kq = lane >> 4;
    const int lr = lane & 15;

    // ---- prologue: A(0)x2, A(1)x2, B(0)x4, A(2)x2 -> 10 outstanding
    f32x4 r0a = gload4(Abase);
    f32x4 r0b = gload4(Abase + 4);
    f32x4 r1a = gload4(Abase + BK);
    f32x4 r1b = gload4(Abase + BK + 4);
#pragma unroll
    for (int i = 0; i < 4; ++i) {
        int sbase = sb0 + i * 64;
        async_lds16(W16t + (size_t)(sbase + lane) * 8, Bflat + (size_t)sbase * 8);
    }
    f32x4 rAa = gload4(Abase + 2 * BK);
    f32x4 rAb = gload4(Abase + 2 * BK + 4);

    asm volatile("s_waitcnt vmcnt(6)" ::: "memory");   // A(0),A(1) ready
    __builtin_amdgcn_sched_barrier(0);
    *reinterpret_cast<half8*>(&Alds[0][aks][arow][0]) = cvt8(r0a, r0b);
    *reinterpret_cast<half8*>(&Alds[1][aks][arow][0]) = cvt8(r1a, r1b);
    asm volatile("s_waitcnt vmcnt(2) lgkmcnt(0)" ::: "memory");  // B(0) done
    __builtin_amdgcn_sched_barrier(0);
    __builtin_amdgcn_s_barrier();

    for (int t2 = 0; t2 < NT; ++t2) {
        const int cur3 = t2 % 3, curB = t2 & 1;
        if (t2 + 1 < NT) {
#pragma unroll
            for (int i = 0; i < 4; ++i) {
                int sbase = sb0 + i * 64;
                async_lds16(W16t + (size_t)(t2 + 1) * 8192 + (size_t)(sbase + lane) * 8,
                            Bflat + (size_t)((t2 + 1) & 1) * 8192 + (size_t)sbase * 8);
            }
        }
        if (t2 + 2 < NT) {
            asm volatile("s_waitcnt vmcnt(4)" ::: "memory");
            __builtin_amdgcn_sched_barrier(0);
            *reinterpret_cast<half8*>(&Alds[(t2 + 2) % 3][aks][arow][0]) = cvt8(rAa, rAb);
        }
        if (t2 + 3 < NT) {
            rAa = gload4(Abase + (t2 + 3) * BK);
            rAb = gload4(Abase + (t2 + 3) * BK + 4);
        }
        half8 af[2], bf[8];
#pragma unroll
        for (int rf = 0; rf < 2; ++rf)
            af[rf] = *reinterpret_cast<half8*>(&Alds[cur3][kq][wr * 32 + rf * 16 + lr][0]);
#pragma unroll
        for (int cf = 0; cf < 8; ++cf) {
            int col = wc * 128 + cf * 16 + lr;
            bf[cf] = *reinterpret_cast<half8*>(
                Bflat + (size_t)curB * 8192 + (size_t)(col * 4 + kq) * 8);
        }
        __builtin_amdgcn_s_setprio(1);
#pragma unroll
        for (int rf = 0; rf < 2; ++rf)
#pragma unroll
            for (int cf = 0; cf < 8; ++cf)
                acc[rf][cf] = __builtin_amdgcn_mfma_f32_16x16x32_f16(
                    af[rf], bf[cf], acc[rf][cf], 0, 0, 0);
        __builtin_amdgcn_s_setprio(0);
        if (t2 < NT - 1) {
            if (t2 + 3 < NT)
                asm volatile("s_waitcnt vmcnt(2) lgkmcnt(0)" ::: "memory");
            else
                asm volatile("s_waitcnt vmcnt(0) lgkmcnt(0)" ::: "memory");
            __builtin_amdgcn_sched_barrier(0);
            __builtin_amdgcn_s_barrier();
        }
    }

    // ---- epilogue
#pragma unroll
    for (int rf = 0; rf < 2; ++rf) {
#pragma unroll
        for (int j = 0; j < 4; ++j) {
            float v = 0.f;
#pragma unroll
            for (int cf = 0; cf < 8; ++cf) {
                int col = wc * 128 + cf * 16 + lr;
                float z = acc[rf][cf][j] + c_s[col];
                v += tanhf(z) * u_s[col];
            }
            v += __shfl_xor(v, 1, 64);
            v += __shfl_xor(v, 2, 64);
            v += __shfl_xor(v, 4, 64);
            v += __shfl_xor(v, 8, 64);
            if (lr == 0) red[wc][wr * 32 + rf * 16 + kq * 4 + j] = v;
        }
    }
    __syncthreads();
    if (tid < 64) y[(size_t)b * SS + s_idx[tid]] = red[0][tid] + red[1][tid];
}

// ============ K34: stats once; 128-row compact list; unroll-4; atomic out ===
// grid = BB*NG; block (b,grp) owns rows grp*128 .. grp*128+127.
__global__ __launch_bounds__(256) void k34(const float* __restrict__ h_i,
                                           const float* __restrict__ y,
                                           const int* __restrict__ yidx,
                                           float* __restrict__ out) {
    const int blk = blockIdx.x;
    const int b = blk >> 4;
    const int grp = blk & (NG - 1);
    const int tid = threadIdx.x;
    const int lane = tid & 63;
    const int wave = tid >> 6;
    __shared__ float rmax[4], rsum[4];
    __shared__ float aval[128];
    __shared__ int slist[128];
    __shared__ int mtot;

    // ---- row stats, once (yidx = source row or -1)
    float beta[8];
    float mx = -INFINITY;
#pragma unroll
    for (int i = 0; i < 8; ++i) {
        int s = tid + i * 256;
        int p = yidx[b * SS + s];
        int pc = p < 0 ? 0 : p;
        float v = (p >= 0) ? y[(size_t)pc * SS + s] : NEGV;
        beta[i] = v;
        mx = fmaxf(mx, v);
    }
    for (int off = 32; off; off >>= 1) mx = fmaxf(mx, __shfl_xor(mx, off, 64));
    if (lane == 0) rmax[wave] = mx;
    __syncthreads();
    mx = fmaxf(fmaxf(rmax[0], rmax[1]), fmaxf(rmax[2], rmax[3]));
    float sum = 0.f;
#pragma unroll
    for (int i = 0; i < 8; ++i) sum += expf(beta[i] - mx);
    for (int off = 32; off; off >>= 1) sum += __shfl_xor(sum, off, 64);
    if (lane == 0) rsum[wave] = sum;
    __syncthreads();
    sum = rsum[0] + rsum[1] + rsum[2] + rsum[3];
    const float inv = 1.f / sum;

    // ---- wave 0 builds the combined compact list for 4 chunks of 32 rows
    if (wave == 0) {
        int base = 0;
#pragma unroll
        for (int cc = 0; cc < 4; ++cc) {
            int s = grp * 128 + cc * 32 + lane;   // lane<32 valid
            float a = 0.f;
            bool nz = false;
            if (lane < 32) {
                int p = yidx[b * SS + s];
                if (p >= 0) {
                    a = expf(y[(size_t)p * SS + s] - mx) * inv;
                    nz = (a != 0.f);
                }
            }
            unsigned long long mk = __ballot(nz);
            if (nz) {
                int off = base + __popcll(mk & ((1ull << lane) - 1));
                slist[off] = s;
                aval[off] = a;
            }
            base += __popcll(mk);
        }
        if (lane == 0) mtot = base;
    }
    __syncthreads();

    // ---- weighted sum over ≤128 rows, unroll-4
    const int m = mtot;
    const float* basep = h_i + (size_t)b * SS * HH;
    f32x4 a0 = {0,0,0,0}, a1 = {0,0,0,0}, a2 = {0,0,0,0}, a3 = {0,0,0,0};
    int i2 = 0;
    for (; i2 + 4 <= m; i2 += 4) {
        float w0 = aval[i2],     w1 = aval[i2 + 1];
        float w2 = aval[i2 + 2], w3 = aval[i2 + 3];
        float4 v0 = *reinterpret_cast<const float4*>(&basep[(size_t)slist[i2]     * HH + tid * 4]);
        float4 v1 = *reinterpret_cast<const float4*>(&basep[(size_t)slist[i2 + 1] * HH + tid * 4]);
        float4 v2 = *reinterpret_cast<const float4*>(&basep[(size_t)slist[i2 + 2] * HH + tid * 4]);
        float4 v3 = *reinterpret_cast<const float4*>(&basep[(size_t)slist[i2 + 3] * HH + tid * 4]);
        a0[0] += w0 * v0.x; a0[1] += w0 * v0.y; a0[2] += w0 * v0.z; a0[3] += w0 * v0.w;
        a1[0] += w1 * v1.x; a1[1] += w1 * v1.y; a1[2] += w1 * v1.z; a1[3] += w1 * v1.w;
        a2[0] += w2 * v2.x; a2[1] += w2 * v2.y; a2[2] += w2 * v2.z; a2[3] += w2 * v2.w;
        a3[0] += w3 * v3.x; a3[1] += w3 * v3.y; a3[2] += w3 * v3.z; a3[3] += w3 * v3.w;
    }
    for (; i2 < m; ++i2) {
        float w0 = aval[i2];
        float4 v0 = *reinterpret_cast<const float4*>(&basep[(size_t)slist[i2] * HH + tid * 4]);
        a0[0] += w0 * v0.x; a0[1] += w0 * v0.y; a0[2] += w0 * v0.z; a0[3] += w0 * v0.w;
    }
    float r0 = (a0[0] + a1[0]) + (a2[0] + a3[0]);
    float r1 = (a0[1] + a1[1]) + (a2[1] + a3[1]);
    float r2 = (a0[2] + a1[2]) + (a2[2] + a3[2]);
    float r3 = (a0[3] + a1[3]) + (a2[3] + a3[3]);
    float* op = out + (size_t)b * HH + tid * 4;
    unsafeAtomicAdd(op + 0, r0);
    unsafeAtomicAdd(op + 1, r1);
    unsafeAtomicAdd(op + 2, r2);
    unsafeAtomicAdd(op + 3, r3);
}

extern "C" void kernel_launch(void* const* d_in, const int* in_sizes, int n_in,
                              void* d_out, int out_size, void* d_ws, size_t ws_size,
                              hipStream_t stream) {
    const float* h_i  = (const float*)d_in[0];
    const float* h_t  = (const float*)d_in[1];
    const int*   mask = (const int*)d_in[2];
    const float* W    = (const float*)d_in[3];
    const float* bias = (const float*)d_in[4];
    const float* u    = (const float*)d_in[5];
    float* out = (float*)d_out;

    float* c        = (float*)d_ws;                        // 8192
    float* y        = c + BB * AA;                         // 65536
    _Float16* W16t  = (_Float16*)(y + BB * SS);            // 262144 f16
    int* sList      = (int*)(W16t + AA * HH);              // 65536
    int* cntb       = sList + BB * SS;                     // 32
    int* yidx       = cntb + BB;                           // 65536

    k_prep<<<2240, 256, 0, stream>>>(W, h_t, bias, mask, W16t, c, sList, cntb, yidx, out);
    k2_mfma<<<1024, 256, 0, stream>>>(h_i, W16t, c, u, sList, cntb, y);
    k34<<<BB * NG, 256, 0, stream>>>(h_i, y, yidx, out);
}